// Round 8
// baseline (84.252 us; speedup 1.0000x reference)
//
#include <hip/hip_runtime.h>
#include <hip/hip_bf16.h>

#define N_NODES 50000
#define N_EDGES 800000
#define D_FEAT 64

// dst bucket sort: bucket = dst>>5 (32 nodes/bucket), 1563 used of 2048
#define NBINS 2048
#define BSORT 100                                    // sort blocks; N_EDGES/BSORT = 8000 exact
#define SORT_CHUNK (N_EDGES / BSORT)                 // 8000
#define NSCAN (NBINS * BSORT)                        // 204800 = 200*1024 exact
#define SCAN_BLOCK 1024
#define SCAN_BLOCKS (NSCAN / SCAN_BLOCK)             // 200
#define AGG_CAP 4096
#define NAGG ((N_NODES + 31) / 32)                   // 1563 buckets

// out-degree histogram: single pass, u8x4-packed LDS counters
#define HCHUNKS 64
#define HCHUNK (N_EDGES / HCHUNKS)                   // 12500 exact
#define HWORDS ((N_NODES + 3) / 4)                   // 12500 u32 = 50 KB LDS

#define CONV_BLOCKS ((N_NODES + 255) / 256)          // 196

// ---------- Phase A: out-degree histogram, LDS u8x4-packed, single pass ----------
__global__ __launch_bounds__(256)
void hist_outdeg_kernel(const int* __restrict__ src, unsigned int* __restrict__ hp32) {
    __shared__ unsigned int lh[HWORDS];  // 4 u8 counters per word
    const int chunk = blockIdx.x;
    const int t = threadIdx.x;
    for (int i = t; i < HWORDS; i += 256) lh[i] = 0u;
    __syncthreads();
    const int4* s4 = (const int4*)(src + chunk * HCHUNK);
    for (int i = t; i < HCHUNK / 4; i += 256) {
        int4 v = s4[i];
        atomicAdd(&lh[v.x >> 2], 1u << ((v.x & 3) * 8));
        atomicAdd(&lh[v.y >> 2], 1u << ((v.y & 3) * 8));
        atomicAdd(&lh[v.z >> 2], 1u << ((v.z & 3) * 8));
        atomicAdd(&lh[v.w >> 2], 1u << ((v.w & 3) * 8));
    }
    __syncthreads();
    for (int w = t; w < HWORDS; w += 256)
        hp32[(size_t)chunk * HWORDS + w] = lh[w];
}

// ---------- Phase B (fused): bucket counts (dst>>5) + rs + optional bf16 staging ----------
// Blocks [0, BSORT): bucket counts. Blocks [BSORT, BSORT+CONV_BLOCKS): per-node
// degree merge + rs = 1/sqrt(deg); if xb != nullptr also xb[v][f] = bf16(x[v][f]*rs[v]).
__global__ __launch_bounds__(256)
void count_rs_conv_kernel(const int* __restrict__ dst, unsigned int* __restrict__ gh,
                          const unsigned char* __restrict__ hp8, float* __restrict__ rs,
                          const float* __restrict__ x, unsigned short* __restrict__ xb) {
    __shared__ unsigned int lh[NBINS];  // 8 KB
    __shared__ float lrs[256];
    const int b = blockIdx.x, t = threadIdx.x;
    if (b < BSORT) {
        for (int i = t; i < NBINS; i += 256) lh[i] = 0;
        __syncthreads();
        const int4* d4 = (const int4*)(dst + b * SORT_CHUNK);
        for (int i = t; i < SORT_CHUNK / 4; i += 256) {
            int4 v = d4[i];
            atomicAdd(&lh[v.x >> 5], 1u);
            atomicAdd(&lh[v.y >> 5], 1u);
            atomicAdd(&lh[v.z >> 5], 1u);
            atomicAdd(&lh[v.w >> 5], 1u);
        }
        __syncthreads();
        for (int i = t; i < NBINS; i += 256) gh[(size_t)i * BSORT + b] = lh[i];  // bin-major
    } else {
        const int nb = (b - BSORT) * 256;      // node base of this chunk
        const int v = nb + t;
        float w = 0.0f;
        if (v < N_NODES) {
            unsigned int s = 0;
            #pragma unroll
            for (int c = 0; c < HCHUNKS; ++c) s += hp8[(size_t)c * (HWORDS * 4) + v];
            w = rsqrtf((float)s);
            rs[v] = w;
        }
        if (xb != nullptr) {
            lrs[t] = w;
            __syncthreads();
            // cooperative, coalesced conversion of this chunk's 256 rows
            #pragma unroll 4
            for (int it = 0; it < 64; ++it) {
                int idx = it * 256 + t;          // element within chunk
                int nl = idx >> 6;               // local node
                int g = nb + nl;
                if (g < N_NODES) {
                    float f = x[(size_t)g * D_FEAT + (idx & 63)] * lrs[nl];
                    xb[(size_t)g * D_FEAT + (idx & 63)] =
                        __hip_bfloat16_raw(__float2bfloat16(f)).x;
                }
            }
        }
    }
}

// ---------- Phase C: exclusive scan over gh[NSCAN], 2 kernels ----------
__global__ __launch_bounds__(SCAN_BLOCK)
void scan_reduce_kernel(const unsigned int* __restrict__ in, unsigned int* __restrict__ partial) {
    __shared__ unsigned int wsum[SCAN_BLOCK / 64];
    int g = blockIdx.x * SCAN_BLOCK + threadIdx.x;   // NSCAN exact multiple
    unsigned int v = in[g];
    for (int off = 32; off > 0; off >>= 1) v += __shfl_down(v, off, 64);
    if ((threadIdx.x & 63) == 0) wsum[threadIdx.x >> 6] = v;
    __syncthreads();
    if (threadIdx.x < SCAN_BLOCK / 64) {
        unsigned int s = wsum[threadIdx.x];
        for (int off = SCAN_BLOCK / 128; off > 0; off >>= 1) s += __shfl_down(s, off, 64);
        if (threadIdx.x == 0) partial[blockIdx.x] = s;
    }
}

__global__ __launch_bounds__(SCAN_BLOCK)
void scan_final_kernel(unsigned int* __restrict__ data, const unsigned int* __restrict__ partial) {
    __shared__ unsigned int arr[SCAN_BLOCK];
    __shared__ unsigned int pbase[256];
    const int t = threadIdx.x;
    const int g = blockIdx.x * SCAN_BLOCK + t;
    if (t < 256) pbase[t] = (t < SCAN_BLOCKS) ? partial[t] : 0u;
    __syncthreads();
    for (int off = 1; off < 256; off <<= 1) {
        unsigned int u = (t < 256 && t >= off) ? pbase[t - off] : 0u;
        __syncthreads();
        if (t < 256 && t >= off) pbase[t] += u;
        __syncthreads();
    }
    const unsigned int base = (blockIdx.x == 0) ? 0u : pbase[blockIdx.x - 1];
    unsigned int v = data[g];
    arr[t] = v;
    __syncthreads();
    for (int off = 1; off < SCAN_BLOCK; off <<= 1) {
        unsigned int u = (t >= off) ? arr[t - off] : 0u;
        __syncthreads();
        arr[t] += u;
        __syncthreads();
    }
    data[g] = base + arr[t] - v;  // exclusive, in-place
}

// ---------- Phase D: scatter keys into buckets via LDS cursors (plain stores) ----------
__global__ __launch_bounds__(256)
void bucket_scatter_kernel(const int* __restrict__ src, const int* __restrict__ dst,
                           const unsigned int* __restrict__ gh, unsigned int* __restrict__ keysB) {
    __shared__ unsigned int cur[NBINS];  // 8 KB
    const int b = blockIdx.x, t = threadIdx.x;
    for (int i = t; i < NBINS; i += 256) cur[i] = gh[(size_t)i * BSORT + b];
    __syncthreads();
    const int4* s4 = (const int4*)(src + b * SORT_CHUNK);
    const int4* d4 = (const int4*)(dst + b * SORT_CHUNK);
    for (int i = t; i < SORT_CHUNK / 4; i += 256) {
        int4 s = s4[i];
        int4 d = d4[i];
        unsigned int p0 = atomicAdd(&cur[d.x >> 5], 1u);
        keysB[p0] = ((unsigned int)d.x << 16) | (unsigned int)s.x;
        unsigned int p1 = atomicAdd(&cur[d.y >> 5], 1u);
        keysB[p1] = ((unsigned int)d.y << 16) | (unsigned int)s.y;
        unsigned int p2 = atomicAdd(&cur[d.z >> 5], 1u);
        keysB[p2] = ((unsigned int)d.z << 16) | (unsigned int)s.z;
        unsigned int p3 = atomicAdd(&cur[d.w >> 5], 1u);
        keysB[p3] = ((unsigned int)d.w << 16) | (unsigned int)s.w;
    }
}

// ---------- Phase E (bf16): block per bucket: counting-sort + wave-per-node gather ----------
__global__ __launch_bounds__(256)
void bucket_aggregate_bf16_kernel(const unsigned short* __restrict__ xb,
                                  const unsigned int* __restrict__ gh,
                                  const unsigned int* __restrict__ keysB,
                                  const float* __restrict__ rs, float* __restrict__ h) {
    __shared__ unsigned int ebuf[AGG_CAP];  // 16 KB
    __shared__ unsigned int ecnt[32];
    __shared__ unsigned int eoff[33];
    const int g = blockIdx.x;
    const int t = threadIdx.x;
    const int lane = t & 63;
    const int w = t >> 6;
    const unsigned int base = gh[(size_t)g * BSORT];
    const unsigned int end  = gh[(size_t)(g + 1) * BSORT];
    const int cnt = (int)(end - base);

    if (cnt > 0 && cnt <= AGG_CAP) {
        if (t < 32) ecnt[t] = 0;
        __syncthreads();
        for (int i = t; i < cnt; i += 256) atomicAdd(&ecnt[(keysB[base + i] >> 16) & 31], 1u);
        __syncthreads();
        if (t == 0) {
            unsigned int r = 0;
            for (int k2 = 0; k2 < 32; ++k2) { eoff[k2] = r; r += ecnt[k2]; }
            eoff[32] = r;
        }
        __syncthreads();
        if (t < 32) ecnt[t] = eoff[t];
        __syncthreads();
        for (int i = t; i < cnt; i += 256) {
            unsigned int k = keysB[base + i];
            ebuf[atomicAdd(&ecnt[(k >> 16) & 31], 1u)] = k;
        }
        __syncthreads();
        for (int nl = w; nl < 32; nl += 4) {
            int node = g * 32 + nl;
            if (node >= N_NODES) continue;
            int jb = (int)eoff[nl], je = (int)eoff[nl + 1];
            float acc = 0.0f;
            int j = jb;
            for (; j + 3 < je; j += 4) {
                unsigned int s0 = ebuf[j] & 0xFFFFu,     s1 = ebuf[j + 1] & 0xFFFFu;
                unsigned int s2 = ebuf[j + 2] & 0xFFFFu, s3 = ebuf[j + 3] & 0xFFFFu;
                unsigned int v0 = xb[(size_t)s0 * D_FEAT + lane];
                unsigned int v1 = xb[(size_t)s1 * D_FEAT + lane];
                unsigned int v2 = xb[(size_t)s2 * D_FEAT + lane];
                unsigned int v3 = xb[(size_t)s3 * D_FEAT + lane];
                acc += __uint_as_float(v0 << 16) + __uint_as_float(v1 << 16);
                acc += __uint_as_float(v2 << 16) + __uint_as_float(v3 << 16);
            }
            for (; j < je; ++j) {
                unsigned int s = ebuf[j] & 0xFFFFu;
                acc += __uint_as_float((unsigned int)xb[(size_t)s * D_FEAT + lane] << 16);
            }
            h[(size_t)node * D_FEAT + lane] = (je > jb) ? acc * rs[node] : 0.0f;
        }
    } else {
        for (int nl = w; nl < 32; nl += 4) {
            int node = g * 32 + nl;
            if (node >= N_NODES) continue;
            float acc = 0.0f;
            int any = 0;
            for (unsigned int j = base; j < end; ++j) {
                unsigned int k = keysB[j];
                if ((int)((k >> 16) & 31) == nl) {
                    acc += __uint_as_float((unsigned int)xb[(size_t)(k & 0xFFFFu) * D_FEAT + lane] << 16);
                    any = 1;
                }
            }
            h[(size_t)node * D_FEAT + lane] = any ? acc * rs[node] : 0.0f;
        }
    }
}

// ---------- Phase E (fp32, tier B): proven round-6 aggregate ----------
__global__ __launch_bounds__(256)
void bucket_aggregate_kernel(const float* __restrict__ x, const unsigned int* __restrict__ gh,
                             const unsigned int* __restrict__ keysB, const float* __restrict__ rs,
                             float* __restrict__ h) {
    __shared__ unsigned int ebuf[AGG_CAP];
    __shared__ unsigned int ecnt[32];
    __shared__ unsigned int eoff[33];
    const int g = blockIdx.x;
    const int t = threadIdx.x;
    const int lane = t & 63;
    const int w = t >> 6;
    const unsigned int base = gh[(size_t)g * BSORT];
    const unsigned int end  = gh[(size_t)(g + 1) * BSORT];
    const int cnt = (int)(end - base);

    if (cnt > 0 && cnt <= AGG_CAP) {
        if (t < 32) ecnt[t] = 0;
        __syncthreads();
        for (int i = t; i < cnt; i += 256) atomicAdd(&ecnt[(keysB[base + i] >> 16) & 31], 1u);
        __syncthreads();
        if (t == 0) {
            unsigned int r = 0;
            for (int k2 = 0; k2 < 32; ++k2) { eoff[k2] = r; r += ecnt[k2]; }
            eoff[32] = r;
        }
        __syncthreads();
        if (t < 32) ecnt[t] = eoff[t];
        __syncthreads();
        for (int i = t; i < cnt; i += 256) {
            unsigned int k = keysB[base + i];
            ebuf[atomicAdd(&ecnt[(k >> 16) & 31], 1u)] = k;
        }
        __syncthreads();
        for (int nl = w; nl < 32; nl += 4) {
            int node = g * 32 + nl;
            if (node >= N_NODES) continue;
            int jb = (int)eoff[nl], je = (int)eoff[nl + 1];
            float acc = 0.0f;
            int j = jb;
            for (; j + 3 < je; j += 4) {
                unsigned int s0 = ebuf[j] & 0xFFFFu,     s1 = ebuf[j + 1] & 0xFFFFu;
                unsigned int s2 = ebuf[j + 2] & 0xFFFFu, s3 = ebuf[j + 3] & 0xFFFFu;
                float w0 = rs[s0], w1 = rs[s1], w2 = rs[s2], w3 = rs[s3];
                acc = fmaf(x[(size_t)s0 * D_FEAT + lane], w0, acc);
                acc = fmaf(x[(size_t)s1 * D_FEAT + lane], w1, acc);
                acc = fmaf(x[(size_t)s2 * D_FEAT + lane], w2, acc);
                acc = fmaf(x[(size_t)s3 * D_FEAT + lane], w3, acc);
            }
            for (; j < je; ++j) {
                unsigned int s = ebuf[j] & 0xFFFFu;
                acc = fmaf(x[(size_t)s * D_FEAT + lane], rs[s], acc);
            }
            h[(size_t)node * D_FEAT + lane] = (je > jb) ? acc * rs[node] : 0.0f;
        }
    } else {
        for (int nl = w; nl < 32; nl += 4) {
            int node = g * 32 + nl;
            if (node >= N_NODES) continue;
            float acc = 0.0f;
            int any = 0;
            for (unsigned int j = base; j < end; ++j) {
                unsigned int k = keysB[j];
                if ((int)((k >> 16) & 31) == nl) {
                    unsigned int s = k & 0xFFFFu;
                    acc = fmaf(x[(size_t)s * D_FEAT + lane], rs[s], acc);
                    any = 1;
                }
            }
            h[(size_t)node * D_FEAT + lane] = any ? acc * rs[node] : 0.0f;
        }
    }
}

// ---------- Fallback (tiny ws): atomic scatter ----------
__global__ void fb_degree_kernel(const int* __restrict__ src, unsigned int* __restrict__ deg,
                                 int n_edges) {
    int i = blockIdx.x * blockDim.x + threadIdx.x;
    int stride = gridDim.x * blockDim.x;
    for (; i < n_edges; i += stride) atomicAdd(&deg[src[i]], 1u);
}
__global__ void fb_scatter_kernel(const float* __restrict__ x, const int* __restrict__ src,
                                  const int* __restrict__ dst, const unsigned int* __restrict__ deg,
                                  float* __restrict__ h, int n_edges) {
    const int lane = threadIdx.x & 63;
    const int wave = (int)((blockIdx.x * blockDim.x + threadIdx.x) >> 6);
    const int nwaves = (int)((gridDim.x * blockDim.x) >> 6);
    for (int e = wave; e < n_edges; e += nwaves) {
        int s = __builtin_amdgcn_readfirstlane(src[e]);
        int d = __builtin_amdgcn_readfirstlane(dst[e]);
        float norm = rsqrtf((float)deg[s] * (float)deg[d]);
        atomicAdd(&h[d * D_FEAT + lane], x[s * D_FEAT + lane] * norm);
    }
}

// ---------- launch ----------
extern "C" void kernel_launch(void* const* d_in, const int* in_sizes, int n_in,
                              void* d_out, int out_size, void* d_ws, size_t ws_size,
                              hipStream_t stream) {
    const float* x   = (const float*)d_in[0];
    const int*   src = (const int*)d_in[1];
    const int*   dst = (const int*)d_in[2];
    float* h = (float*)d_out;

    // Workspace layout:
    //   keysB : N_EDGES u32 (3.2 MB) -- aliased with hp32 (64*12500 u32); hp32 is fully
    //           consumed in count_rs_conv before bucket_scatter overwrites keysB.
    //   gh    : NSCAN u32 (0.82 MB)
    //   rs    : N_NODES f32 (200 KB)
    //   spart : 256 u32
    //   xb    : N_NODES*D_FEAT u16 (6.4 MB)   [tier A only]
    size_t off = 0;
    unsigned int*  keysB = (unsigned int*)((char*)d_ws + off);  off += (size_t)N_EDGES * 4;
    unsigned int*  hp32  = keysB;
    unsigned int*  gh    = (unsigned int*)((char*)d_ws + off);  off += (size_t)NSCAN * 4;
    float*         rs    = (float*)((char*)d_ws + off);         off += (size_t)N_NODES * 4;
    unsigned int*  spart = (unsigned int*)((char*)d_ws + off);  off += 256 * 4;
    const size_t off_b = off;                                   // tier B requirement
    unsigned short* xb  = (unsigned short*)((char*)d_ws + off); off += (size_t)N_NODES * D_FEAT * 2;
    const size_t off_a = off;                                   // tier A requirement

    if (ws_size >= off_b) {
        const bool tierA = (ws_size >= off_a);
        // No memsets: every read workspace element is fully overwritten first.
        hist_outdeg_kernel<<<dim3(HCHUNKS), dim3(256), 0, stream>>>(src, hp32);
        count_rs_conv_kernel<<<dim3(BSORT + CONV_BLOCKS), dim3(256), 0, stream>>>(
            dst, gh, (const unsigned char*)hp32, rs, x, tierA ? xb : nullptr);
        scan_reduce_kernel<<<dim3(SCAN_BLOCKS), dim3(SCAN_BLOCK), 0, stream>>>(gh, spart);
        scan_final_kernel<<<dim3(SCAN_BLOCKS), dim3(SCAN_BLOCK), 0, stream>>>(gh, spart);
        bucket_scatter_kernel<<<dim3(BSORT), dim3(256), 0, stream>>>(src, dst, gh, keysB);
        if (tierA) {
            bucket_aggregate_bf16_kernel<<<dim3(NAGG), dim3(256), 0, stream>>>(xb, gh, keysB, rs, h);
        } else {
            bucket_aggregate_kernel<<<dim3(NAGG), dim3(256), 0, stream>>>(x, gh, keysB, rs, h);
        }
    } else {
        // Fallback: atomic scatter (any ws >= 200 KB).
        unsigned int* deg = (unsigned int*)d_ws;
        hipMemsetAsync(deg, 0, N_NODES * sizeof(unsigned int), stream);
        hipMemsetAsync(d_out, 0, (size_t)out_size * sizeof(float), stream);
        fb_degree_kernel<<<dim3(1024), dim3(256), 0, stream>>>(src, deg, N_EDGES);
        fb_scatter_kernel<<<dim3(2048), dim3(256), 0, stream>>>(x, src, dst, deg, h, N_EDGES);
    }
}

// Round 9
// 65.330 us; speedup vs baseline: 1.2896x; 1.2896x over previous
//
#include <hip/hip_runtime.h>

#define N_NODES 50000
#define N_EDGES 800000
#define D_FEAT 64

// dst bucket sort: bucket = dst>>5 (32 nodes/bucket), 1563 used of 2048
#define NBINS 2048
#define BSORT 100                                    // sort blocks; N_EDGES/BSORT = 8000 exact
#define SORT_CHUNK (N_EDGES / BSORT)                 // 8000
#define NSCAN (NBINS * BSORT)                        // 204800 = 200*1024 exact
#define SCAN_BLOCK 1024
#define SCAN_BLOCKS (NSCAN / SCAN_BLOCK)             // 200
#define AGG_CAP 4096
#define NAGG ((N_NODES + 31) / 32)                   // 1563 buckets

// out-degree histogram: single pass, u8x4-packed LDS counters
#define HCHUNKS 64
#define HCHUNK (N_EDGES / HCHUNKS)                   // 12500 exact
#define HWORDS ((N_NODES + 3) / 4)                   // 12500 u32 = 50 KB LDS

#define RS_BLOCKS ((N_NODES + 255) / 256)            // 196

// ---------- Kernel 1 (fused): src out-degree histogram  ||  dst bucket counts ----------
// Blocks [0, HCHUNKS): LDS u8x4 histogram of one 12500-edge src chunk.
// Blocks [HCHUNKS, HCHUNKS+BSORT): LDS bucket count of one 8000-edge dst chunk.
__global__ __launch_bounds__(256)
void hist_count_kernel(const int* __restrict__ src, const int* __restrict__ dst,
                       unsigned int* __restrict__ hp32, unsigned int* __restrict__ gh) {
    __shared__ unsigned int lh[HWORDS];  // 50 KB; count path uses first NBINS words
    const int b = blockIdx.x, t = threadIdx.x;
    if (b < HCHUNKS) {
        for (int i = t; i < HWORDS; i += 256) lh[i] = 0u;
        __syncthreads();
        const int4* s4 = (const int4*)(src + b * HCHUNK);
        for (int i = t; i < HCHUNK / 4; i += 256) {
            int4 v = s4[i];
            atomicAdd(&lh[v.x >> 2], 1u << ((v.x & 3) * 8));
            atomicAdd(&lh[v.y >> 2], 1u << ((v.y & 3) * 8));
            atomicAdd(&lh[v.z >> 2], 1u << ((v.z & 3) * 8));
            atomicAdd(&lh[v.w >> 2], 1u << ((v.w & 3) * 8));
        }
        __syncthreads();
        for (int w = t; w < HWORDS; w += 256)
            hp32[(size_t)b * HWORDS + w] = lh[w];
    } else {
        const int cb = b - HCHUNKS;
        for (int i = t; i < NBINS; i += 256) lh[i] = 0;
        __syncthreads();
        const int4* d4 = (const int4*)(dst + cb * SORT_CHUNK);
        for (int i = t; i < SORT_CHUNK / 4; i += 256) {
            int4 v = d4[i];
            atomicAdd(&lh[v.x >> 5], 1u);
            atomicAdd(&lh[v.y >> 5], 1u);
            atomicAdd(&lh[v.z >> 5], 1u);
            atomicAdd(&lh[v.w >> 5], 1u);
        }
        __syncthreads();
        for (int i = t; i < NBINS; i += 256) gh[(size_t)i * BSORT + cb] = lh[i];  // bin-major
    }
}

// ---------- Kernel 2 (fused): scan block-reduce  ||  degree merge + rs ----------
// Blocks [0, SCAN_BLOCKS): per-1024-chunk sum of gh.
// Blocks [SCAN_BLOCKS, SCAN_BLOCKS+RS_BLOCKS): rs[v] = rsqrt(sum of 64 u8 partials).
__global__ __launch_bounds__(SCAN_BLOCK)
void scanred_rs_kernel(const unsigned int* __restrict__ gh, unsigned int* __restrict__ partial,
                       const unsigned char* __restrict__ hp8, float* __restrict__ rs) {
    const int b = blockIdx.x;
    if (b < SCAN_BLOCKS) {
        __shared__ unsigned int wsum[SCAN_BLOCK / 64];
        int g = b * SCAN_BLOCK + threadIdx.x;
        unsigned int v = gh[g];
        for (int off = 32; off > 0; off >>= 1) v += __shfl_down(v, off, 64);
        if ((threadIdx.x & 63) == 0) wsum[threadIdx.x >> 6] = v;
        __syncthreads();
        if (threadIdx.x < SCAN_BLOCK / 64) {
            unsigned int s = wsum[threadIdx.x];
            for (int off = SCAN_BLOCK / 128; off > 0; off >>= 1) s += __shfl_down(s, off, 64);
            if (threadIdx.x == 0) partial[b] = s;
        }
    } else {
        if (threadIdx.x < 256) {
            int v = (b - SCAN_BLOCKS) * 256 + threadIdx.x;
            if (v < N_NODES) {
                unsigned int s = 0;
                #pragma unroll
                for (int c = 0; c < HCHUNKS; ++c) s += hp8[(size_t)c * (HWORDS * 4) + v];
                rs[v] = rsqrtf((float)s);
            }
        }
    }
}

// ---------- Kernel 3: scan finalize (in-LDS re-scan of the 200 partials) ----------
__global__ __launch_bounds__(SCAN_BLOCK)
void scan_final_kernel(unsigned int* __restrict__ data, const unsigned int* __restrict__ partial) {
    __shared__ unsigned int arr[SCAN_BLOCK];
    __shared__ unsigned int pbase[256];
    const int t = threadIdx.x;
    const int g = blockIdx.x * SCAN_BLOCK + t;
    if (t < 256) pbase[t] = (t < SCAN_BLOCKS) ? partial[t] : 0u;
    __syncthreads();
    for (int off = 1; off < 256; off <<= 1) {
        unsigned int u = (t < 256 && t >= off) ? pbase[t - off] : 0u;
        __syncthreads();
        if (t < 256 && t >= off) pbase[t] += u;
        __syncthreads();
    }
    const unsigned int base = (blockIdx.x == 0) ? 0u : pbase[blockIdx.x - 1];
    unsigned int v = data[g];
    arr[t] = v;
    __syncthreads();
    for (int off = 1; off < SCAN_BLOCK; off <<= 1) {
        unsigned int u = (t >= off) ? arr[t - off] : 0u;
        __syncthreads();
        arr[t] += u;
        __syncthreads();
    }
    data[g] = base + arr[t] - v;  // exclusive, in-place
}

// ---------- Kernel 4: scatter keys into buckets via LDS cursors (plain stores) ----------
__global__ __launch_bounds__(256)
void bucket_scatter_kernel(const int* __restrict__ src, const int* __restrict__ dst,
                           const unsigned int* __restrict__ gh, unsigned int* __restrict__ keysB) {
    __shared__ unsigned int cur[NBINS];  // 8 KB
    const int b = blockIdx.x, t = threadIdx.x;
    for (int i = t; i < NBINS; i += 256) cur[i] = gh[(size_t)i * BSORT + b];
    __syncthreads();
    const int4* s4 = (const int4*)(src + b * SORT_CHUNK);
    const int4* d4 = (const int4*)(dst + b * SORT_CHUNK);
    for (int i = t; i < SORT_CHUNK / 4; i += 256) {
        int4 s = s4[i];
        int4 d = d4[i];
        unsigned int p0 = atomicAdd(&cur[d.x >> 5], 1u);
        keysB[p0] = ((unsigned int)d.x << 16) | (unsigned int)s.x;
        unsigned int p1 = atomicAdd(&cur[d.y >> 5], 1u);
        keysB[p1] = ((unsigned int)d.y << 16) | (unsigned int)s.y;
        unsigned int p2 = atomicAdd(&cur[d.z >> 5], 1u);
        keysB[p2] = ((unsigned int)d.z << 16) | (unsigned int)s.z;
        unsigned int p3 = atomicAdd(&cur[d.w >> 5], 1u);
        keysB[p3] = ((unsigned int)d.w << 16) | (unsigned int)s.w;
    }
}

// ---------- Kernel 5: block per bucket (32 nodes): LDS counting-sort + wave-per-node gather ----------
__global__ __launch_bounds__(256)
void bucket_aggregate_kernel(const float* __restrict__ x, const unsigned int* __restrict__ gh,
                             const unsigned int* __restrict__ keysB, const float* __restrict__ rs,
                             float* __restrict__ h) {
    __shared__ unsigned int ebuf[AGG_CAP];  // 16 KB
    __shared__ unsigned int ecnt[32];
    __shared__ unsigned int eoff[33];
    const int g = blockIdx.x;
    const int t = threadIdx.x;
    const int lane = t & 63;
    const int w = t >> 6;
    const unsigned int base = gh[(size_t)g * BSORT];
    const unsigned int end  = gh[(size_t)(g + 1) * BSORT];
    const int cnt = (int)(end - base);

    if (cnt > 0 && cnt <= AGG_CAP) {  // block-uniform branch
        if (t < 32) ecnt[t] = 0;
        __syncthreads();
        for (int i = t; i < cnt; i += 256) atomicAdd(&ecnt[(keysB[base + i] >> 16) & 31], 1u);
        __syncthreads();
        if (t == 0) {
            unsigned int r = 0;
            for (int k2 = 0; k2 < 32; ++k2) { eoff[k2] = r; r += ecnt[k2]; }
            eoff[32] = r;
        }
        __syncthreads();
        if (t < 32) ecnt[t] = eoff[t];  // reuse as cursors
        __syncthreads();
        for (int i = t; i < cnt; i += 256) {
            unsigned int k = keysB[base + i];
            ebuf[atomicAdd(&ecnt[(k >> 16) & 31], 1u)] = k;
        }
        __syncthreads();
        for (int nl = w; nl < 32; nl += 4) {
            int node = g * 32 + nl;
            if (node >= N_NODES) continue;
            int jb = (int)eoff[nl], je = (int)eoff[nl + 1];
            float acc = 0.0f;
            int j = jb;
            for (; j + 3 < je; j += 4) {
                unsigned int s0 = ebuf[j] & 0xFFFFu,     s1 = ebuf[j + 1] & 0xFFFFu;
                unsigned int s2 = ebuf[j + 2] & 0xFFFFu, s3 = ebuf[j + 3] & 0xFFFFu;
                float w0 = rs[s0], w1 = rs[s1], w2 = rs[s2], w3 = rs[s3];
                acc = fmaf(x[(size_t)s0 * D_FEAT + lane], w0, acc);
                acc = fmaf(x[(size_t)s1 * D_FEAT + lane], w1, acc);
                acc = fmaf(x[(size_t)s2 * D_FEAT + lane], w2, acc);
                acc = fmaf(x[(size_t)s3 * D_FEAT + lane], w3, acc);
            }
            for (; j < je; ++j) {
                unsigned int s = ebuf[j] & 0xFFFFu;
                acc = fmaf(x[(size_t)s * D_FEAT + lane], rs[s], acc);
            }
            h[(size_t)node * D_FEAT + lane] = (je > jb) ? acc * rs[node] : 0.0f;
        }
    } else {
        // cnt == 0 (write zeros) or pathological overflow: filter directly from global.
        for (int nl = w; nl < 32; nl += 4) {
            int node = g * 32 + nl;
            if (node >= N_NODES) continue;
            float acc = 0.0f;
            int any = 0;
            for (unsigned int j = base; j < end; ++j) {
                unsigned int k = keysB[j];
                if ((int)((k >> 16) & 31) == nl) {
                    unsigned int s = k & 0xFFFFu;
                    acc = fmaf(x[(size_t)s * D_FEAT + lane], rs[s], acc);
                    any = 1;
                }
            }
            h[(size_t)node * D_FEAT + lane] = any ? acc * rs[node] : 0.0f;
        }
    }
}

// ---------- Fallback (tiny ws): atomic scatter ----------
__global__ void fb_degree_kernel(const int* __restrict__ src, unsigned int* __restrict__ deg,
                                 int n_edges) {
    int i = blockIdx.x * blockDim.x + threadIdx.x;
    int stride = gridDim.x * blockDim.x;
    for (; i < n_edges; i += stride) atomicAdd(&deg[src[i]], 1u);
}
__global__ void fb_scatter_kernel(const float* __restrict__ x, const int* __restrict__ src,
                                  const int* __restrict__ dst, const unsigned int* __restrict__ deg,
                                  float* __restrict__ h, int n_edges) {
    const int lane = threadIdx.x & 63;
    const int wave = (int)((blockIdx.x * blockDim.x + threadIdx.x) >> 6);
    const int nwaves = (int)((gridDim.x * blockDim.x) >> 6);
    for (int e = wave; e < n_edges; e += nwaves) {
        int s = __builtin_amdgcn_readfirstlane(src[e]);
        int d = __builtin_amdgcn_readfirstlane(dst[e]);
        float norm = rsqrtf((float)deg[s] * (float)deg[d]);
        atomicAdd(&h[d * D_FEAT + lane], x[s * D_FEAT + lane] * norm);
    }
}

// ---------- launch ----------
extern "C" void kernel_launch(void* const* d_in, const int* in_sizes, int n_in,
                              void* d_out, int out_size, void* d_ws, size_t ws_size,
                              hipStream_t stream) {
    const float* x   = (const float*)d_in[0];
    const int*   src = (const int*)d_in[1];
    const int*   dst = (const int*)d_in[2];
    float* h = (float*)d_out;

    // Workspace layout (~4.25 MB):
    //   keysB : N_EDGES u32 (3.2 MB) -- aliased with hp32 (64*12500 u32 = 3.2 MB);
    //           hp32 fully consumed by scanred_rs before bucket_scatter writes keysB.
    //   gh    : NSCAN u32 (0.82 MB)
    //   rs    : N_NODES f32 (200 KB)
    //   spart : 256 u32
    size_t off = 0;
    unsigned int*  keysB = (unsigned int*)((char*)d_ws + off);  off += (size_t)N_EDGES * 4;
    unsigned int*  hp32  = keysB;
    unsigned int*  gh    = (unsigned int*)((char*)d_ws + off);  off += (size_t)NSCAN * 4;
    float*         rs    = (float*)((char*)d_ws + off);         off += (size_t)N_NODES * 4;
    unsigned int*  spart = (unsigned int*)((char*)d_ws + off);  off += 256 * 4;

    if (ws_size >= off) {
        // No memsets: every workspace/output element is fully overwritten.
        hist_count_kernel<<<dim3(HCHUNKS + BSORT), dim3(256), 0, stream>>>(src, dst, hp32, gh);
        scanred_rs_kernel<<<dim3(SCAN_BLOCKS + RS_BLOCKS), dim3(SCAN_BLOCK), 0, stream>>>(
            gh, spart, (const unsigned char*)hp32, rs);
        scan_final_kernel<<<dim3(SCAN_BLOCKS), dim3(SCAN_BLOCK), 0, stream>>>(gh, spart);
        bucket_scatter_kernel<<<dim3(BSORT), dim3(256), 0, stream>>>(src, dst, gh, keysB);
        bucket_aggregate_kernel<<<dim3(NAGG), dim3(256), 0, stream>>>(x, gh, keysB, rs, h);
    } else {
        // Fallback: atomic scatter (any ws >= 200 KB).
        unsigned int* deg = (unsigned int*)d_ws;
        hipMemsetAsync(deg, 0, N_NODES * sizeof(unsigned int), stream);
        hipMemsetAsync(d_out, 0, (size_t)out_size * sizeof(float), stream);
        fb_degree_kernel<<<dim3(1024), dim3(256), 0, stream>>>(src, deg, N_EDGES);
        fb_scatter_kernel<<<dim3(2048), dim3(256), 0, stream>>>(x, src, dst, deg, h, N_EDGES);
    }
}